// Round 11
// baseline (407.289 us; speedup 1.0000x reference)
//
#include <hip/hip_runtime.h>
#include <math.h>
#include <stdint.h>

namespace {

typedef __attribute__((ext_vector_type(8))) short s8v;   // 8 bf16 (MFMA A/B frag)
typedef __attribute__((ext_vector_type(4))) float f4v;   // MFMA C/D frag
typedef unsigned short u16;

__device__ __forceinline__ float fexp2(float x) {  // native v_exp_f32 (2^x)
  return __builtin_amdgcn_exp2f(x);
}

__device__ __forceinline__ u16 f2bf(float f) {  // RTNE
  union { float f; uint32_t u; } v; v.f = f;
  uint32_t r = v.u + 0x7fffu + ((v.u >> 16) & 1u);
  return (u16)(r >> 16);
}
__device__ __forceinline__ float bf2f(u16 h) {
  union { uint32_t u; float f; } v; v.u = ((uint32_t)h) << 16;
  return v.f;
}
__device__ __forceinline__ uint32_t pk2r(float a, float b) {  // RTNE pair pack
  return (uint32_t)f2bf(a) | ((uint32_t)f2bf(b) << 16);
}
__device__ __forceinline__ uint32_t pk2(float a, float b) {  // fast round-half-up
  union { float f; uint32_t u; } x, y; x.f = a; y.f = b;
  return ((x.u + 0x8000u) >> 16) | ((y.u + 0x8000u) & 0xffff0000u);
}
__device__ __forceinline__ float sigmoidf_(float x) { return 1.0f / (1.0f + __expf(-x)); }

__device__ __forceinline__ void gload16(const u16* g, u16* l) {
  __builtin_amdgcn_global_load_lds(
      (const __attribute__((address_space(1))) void*)g,
      (__attribute__((address_space(3))) void*)l, 16, 0, 0);
}

// ---------------------------------------------------------------------------
// fp32 -> bf16 conversion; equal jobs of 262144 float4-groups.
// Blocks (y==0, x<4) additionally zero Vtot (16 KB) for qkv's atomic sums.
// ---------------------------------------------------------------------------
struct CvtJob { const float* src; u16* dst; };
struct CvtArgs { CvtJob j[18]; float* vz; };

__global__ __launch_bounds__(256) void cvt_kernel(CvtArgs a) {
  if (blockIdx.y == 0 && blockIdx.x < 4) {
    float4 z; z.x = 0.f; z.y = 0.f; z.z = 0.f; z.w = 0.f;
    ((float4*)a.vz)[blockIdx.x * 256 + threadIdx.x] = z;
  }
  const CvtJob jb = a.j[blockIdx.y];
  const int i = blockIdx.x * 256 + threadIdx.x;
  const float4 v = ((const float4*)jb.src)[i];
  uint2 pk;
  pk.x = pk2r(v.x, v.y);
  pk.y = pk2r(v.z, v.w);
  ((uint2*)jb.dst)[i] = pk;
}

// ---------------------------------------------------------------------------
// Fused QKV projection, 128x128 tile, BK=64 -- DIRECT-TO-REGISTER, no LDS,
// no barriers. The 16x16x32 A/B fragments are natural b128 loads from
// row-major global (lane row = lr, 8 contiguous k at lq*8); each wave
// register-double-buffers its own fragments (prefetch c+1 during MFMA of c),
// so there is no collective vmcnt(0) stall -- waves pipeline independently.
// Wave-pair read duplication is absorbed by L1/L2.
// Q/K compute C^T via mfma(b,a) -> uint2 stores; V keeps mfma(a,b)
// (s-packed Vt[b][h][d][s] store) and atomically accumulates Vtot.
// ---------------------------------------------------------------------------
__global__ __launch_bounds__(256, 2) void qkv_gemm(
    const u16* __restrict__ xb,
    const u16* __restrict__ Wqb, const u16* __restrict__ Wkb, const u16* __restrict__ Wvb,
    const float* __restrict__ bq, const float* __restrict__ bk, const float* __restrict__ bv,
    const float* __restrict__ mem,
    u16* __restrict__ Qb, u16* __restrict__ Kb, u16* __restrict__ Vt,
    float* __restrict__ Vtot) {
  const int t = threadIdx.x;
  const int nb = blockIdx.x, mb = blockIdx.y;
  const int sel = nb >> 3;
  const u16* W = sel == 0 ? Wqb : (sel == 1 ? Wkb : Wvb);
  const float* bias = sel == 0 ? bq : (sel == 1 ? bk : bv);
  const int m0 = mb * 128, n0 = (nb & 7) * 128;
  const f4v fz = {0.f, 0.f, 0.f, 0.f};
  f4v acc[4][4];
#pragma unroll
  for (int i = 0; i < 4; ++i)
#pragma unroll
    for (int j = 0; j < 4; ++j) acc[i][j] = fz;

  const int l = t & 63, w = t >> 6, wm = w >> 1, wn = w & 1;
  const int lr = l & 15, lq = l >> 4;

  const u16* Ap = xb + (size_t)(m0 + wm * 64 + lr) * 1024 + lq * 8;
  const u16* Bp = W + (size_t)(n0 + wn * 64 + lr) * 1024 + lq * 8;

  s8v afb[2][2][4], bfb[2][2][4];  // [buf][ks][tile] register double-buffer

#define QLOAD(bsel, c)                                                         \
  _Pragma("unroll") for (int ks_ = 0; ks_ < 2; ++ks_)                          \
  _Pragma("unroll") for (int i2 = 0; i2 < 4; ++i2) {                           \
    afb[bsel][ks_][i2] = *(const s8v*)(Ap + i2 * 16384 + (c) * 64 + ks_ * 32); \
    bfb[bsel][ks_][i2] = *(const s8v*)(Bp + i2 * 16384 + (c) * 64 + ks_ * 32); \
  }

  QLOAD(0, 0);

  if (sel < 2) {  // ---- Q/K: swapped operands (C^T) ----
#pragma unroll
    for (int c = 0; c < 16; ++c) {
      const int cur = c & 1;
      if (c < 15) { QLOAD(cur ^ 1, c + 1); }  // in flight during MFMA
#pragma unroll
      for (int ks = 0; ks < 2; ++ks)
#pragma unroll
        for (int mi = 0; mi < 4; ++mi)
#pragma unroll
          for (int ni = 0; ni < 4; ++ni)
            acc[mi][ni] = __builtin_amdgcn_mfma_f32_16x16x32_bf16(
                bfb[cur][ks][ni], afb[cur][ks][mi], acc[mi][ni], 0, 0, 0);
    }
    u16* dst = (sel == 0) ? Qb : Kb;
#pragma unroll
    for (int mi = 0; mi < 4; ++mi)
#pragma unroll
      for (int ni = 0; ni < 4; ++ni) {
        const int m = m0 + wm * 64 + mi * 16 + lr;
        const int nb4 = n0 + wn * 64 + ni * 16 + lq * 4;
        const float4 b4 = *(const float4*)&bias[nb4];
        uint2 pk;
        pk.x = pk2r(acc[mi][ni][0] + b4.x, acc[mi][ni][1] + b4.y);
        pk.y = pk2r(acc[mi][ni][2] + b4.z, acc[mi][ni][3] + b4.w);
        *(uint2*)(dst + (size_t)m * 1024 + nb4) = pk;
      }
  } else {  // ---- V: normal operands (s-packed Vt store) + Vtot atomics ----
#pragma unroll
    for (int c = 0; c < 16; ++c) {
      const int cur = c & 1;
      if (c < 15) { QLOAD(cur ^ 1, c + 1); }
#pragma unroll
      for (int ks = 0; ks < 2; ++ks)
#pragma unroll
        for (int mi = 0; mi < 4; ++mi)
#pragma unroll
          for (int ni = 0; ni < 4; ++ni)
            acc[mi][ni] = __builtin_amdgcn_mfma_f32_16x16x32_bf16(
                afb[cur][ks][mi], bfb[cur][ks][ni], acc[mi][ni], 0, 0, 0);
    }
    const int b = m0 >> 10;
    float vpart[4] = {0.f, 0.f, 0.f, 0.f};
#pragma unroll
    for (int mi = 0; mi < 4; ++mi)
#pragma unroll
      for (int ni = 0; ni < 4; ++ni) {
        const int mrow = m0 + wm * 64 + mi * 16 + lq * 4;
        const int ncol = n0 + wn * 64 + ni * 16 + lr;
        const int h = ncol >> 6, d = ncol & 63;
        const float bi = bias[ncol];
        float tv[4];
#pragma unroll
        for (int r = 0; r < 4; ++r)
          tv[r] = (acc[mi][ni][r] + bi) * sigmoidf_(mem[(size_t)(mrow + r) * 1024 + ncol]);
        vpart[ni] += (tv[0] + tv[1]) + (tv[2] + tv[3]);
        const int s = mrow & 1023;
        uint2 pk;
        pk.x = pk2r(tv[0], tv[1]);
        pk.y = pk2r(tv[2], tv[3]);
        *(uint2*)(Vt + ((size_t)((b * 16 + h) * 64 + d)) * 1024 + s) = pk;
      }
#pragma unroll
    for (int ni = 0; ni < 4; ++ni) {
      const int ncol = n0 + wn * 64 + ni * 16 + lr;
      atomicAdd(&Vtot[(size_t)(b * 16 + (ncol >> 6)) * 64 + (ncol & 63)], vpart[ni]);
    }
  }
#undef QLOAD
}

// ---------------------------------------------------------------------------
// 64(M) x 128(N) GEMM, BK=64 -- direct-to-register, no LDS, no barriers,
// register dbuf, swapped operands (C^T). K = NC*64 (compile-time).
// MODE 0: out = A @ W^T + bias (fp32 out, float4 stores)
// MODE 1: gate: A = [Ab | A2b] (K=2048); out = Ab * sigmoid(A@Wg^T+bg) (bf16)
// ---------------------------------------------------------------------------
template <int MODE, int NC>
__global__ __launch_bounds__(256, 2) void gemm64(
    const u16* __restrict__ Ab, const u16* __restrict__ A2b,
    const u16* __restrict__ W, const float* __restrict__ bias,
    u16* __restrict__ outb, float* __restrict__ outf) {
  constexpr int K = NC * 64;
  const int t = threadIdx.x, l = t & 63, w = t >> 6;
  const int wm = w >> 1, wn = w & 1, lr = l & 15, lq = l >> 4;
  const int m0 = blockIdx.y * 64, n0 = blockIdx.x * 128;
  const f4v fz = {0.f, 0.f, 0.f, 0.f};
  f4v acc[2][4];
#pragma unroll
  for (int i = 0; i < 2; ++i)
#pragma unroll
    for (int j = 0; j < 4; ++j) acc[i][j] = fz;

  const u16* Apt = Ab + (size_t)(m0 + wm * 32 + lr) * 1024 + lq * 8;
  const u16* A2pt = (MODE == 1)
      ? A2b + (size_t)(m0 + wm * 32 + lr) * 1024 + lq * 8 : Apt;
  const u16* Bpt = W + (size_t)(n0 + wn * 64 + lr) * K + lq * 8;

  s8v afb[2][2][2], bfb[2][2][4];

#define GLOAD(bsel, c)                                                         \
  {                                                                            \
    const int kk_ = (c) * 64;                                                  \
    const u16* Ae_ = (MODE == 1 && kk_ >= 1024) ? A2pt + (kk_ - 1024)          \
                                                : Apt + kk_;                   \
    _Pragma("unroll") for (int ks_ = 0; ks_ < 2; ++ks_) {                      \
      _Pragma("unroll") for (int i2 = 0; i2 < 2; ++i2)                         \
        afb[bsel][ks_][i2] = *(const s8v*)(Ae_ + i2 * 16384 + ks_ * 32);       \
      _Pragma("unroll") for (int i2 = 0; i2 < 4; ++i2)                         \
        bfb[bsel][ks_][i2] =                                                   \
            *(const s8v*)(Bpt + (size_t)i2 * 16 * K + kk_ + ks_ * 32);         \
    }                                                                          \
  }

  GLOAD(0, 0);
#pragma unroll
  for (int c = 0; c < NC; ++c) {
    const int cur = c & 1;
    if (c + 1 < NC) { GLOAD(cur ^ 1, c + 1); }
#pragma unroll
    for (int ks = 0; ks < 2; ++ks)
#pragma unroll
      for (int mi = 0; mi < 2; ++mi)
#pragma unroll
        for (int ni = 0; ni < 4; ++ni)
          acc[mi][ni] = __builtin_amdgcn_mfma_f32_16x16x32_bf16(
              bfb[cur][ks][ni], afb[cur][ks][mi], acc[mi][ni], 0, 0, 0);
  }
#undef GLOAD

#pragma unroll
  for (int mi = 0; mi < 2; ++mi)
#pragma unroll
    for (int ni = 0; ni < 4; ++ni) {
      const int m = m0 + wm * 32 + mi * 16 + lr;
      const int nb4 = n0 + wn * 64 + ni * 16 + lq * 4;
      const float4 b4 = *(const float4*)&bias[nb4];
      if (MODE == 0) {
        float4 o;
        o.x = acc[mi][ni][0] + b4.x; o.y = acc[mi][ni][1] + b4.y;
        o.z = acc[mi][ni][2] + b4.z; o.w = acc[mi][ni][3] + b4.w;
        *(float4*)(outf + (size_t)m * 1024 + nb4) = o;
      } else {
        const uint2 a2 = *(const uint2*)(Ab + (size_t)m * 1024 + nb4);
        float cx[4] = {bf2f((u16)(a2.x & 0xffff)), bf2f((u16)(a2.x >> 16)),
                       bf2f((u16)(a2.y & 0xffff)), bf2f((u16)(a2.y >> 16))};
        float g[4];
        g[0] = cx[0] * sigmoidf_(acc[mi][ni][0] + b4.x);
        g[1] = cx[1] * sigmoidf_(acc[mi][ni][1] + b4.y);
        g[2] = cx[2] * sigmoidf_(acc[mi][ni][2] + b4.z);
        g[3] = cx[3] * sigmoidf_(acc[mi][ni][3] + b4.w);
        uint2 pk;
        pk.x = pk2r(g[0], g[1]);
        pk.y = pk2r(g[2], g[3]);
        *(uint2*)(outb + (size_t)m * 1024 + nb4) = pk;
      }
    }
}

// ---------------------------------------------------------------------------
// MFMA flash attention with far-field truncation (round-10 structure).
// ---------------------------------------------------------------------------
__global__ __launch_bounds__(256) void attn_mfma(
    const u16* __restrict__ Qb, const u16* __restrict__ Kb,
    const u16* __restrict__ SPb, const u16* __restrict__ Vt,
    const float* __restrict__ tau, const float* __restrict__ Vtot,
    u16* __restrict__ CTXb) {
  __shared__ u16 kbuf[4096], skbuf[4096], vbuf[4096];
  __shared__ u16 pbuf[4][16 * 64];  // per-wave P[i][j], XOR-swizzled 16B chunks
  const int t = threadIdx.x, l = t & 63, w = t >> 6;
  const int lr = l & 15, lq = l >> 4;
  const int p = blockIdx.x;
  const int g = (p & 7) + 8 * (p >> 7);   // bh-group 0..63
  const int qt = (p >> 3) & 15;
  const int h = g & 15, b = g >> 4;

  const float tv_ = tau[h];
  const float c2 = 1.44269504088896f / tv_;     // log2e / tau
  const float K0 = 0.125f * 1.44269504088896f;  // scale * log2e
  int rad = (int)ceilf(tv_ * 0.171875f);  // 11/64: far scores <6e-5 -> P==1
  if (rad > 15) rad = 15;
  const int jlo = (qt - rad < 0) ? 0 : qt - rad;
  const int jhi = (qt + rad > 15) ? 15 : qt + rad;
  const int farCnt = 16 - (jhi - jlo + 1);

  float cN[4], cNi[4], cR[4], cRi[4];
#pragma unroll
  for (int i = 0; i < 4; ++i) {
    cN[i]  = fexp2(c2 * (float)(i * 16));
    cNi[i] = fexp2(-c2 * (float)(i * 16));
    cR[i]  = fexp2(c2 * (float)(lq * 4 + i));
    cRi[i] = fexp2(-c2 * (float)(lq * 4 + i));
  }

  s8v qf[2], sf[2];
  {
    const size_t base = ((size_t)(b * 1024 + qt * 64 + w * 16 + lr)) * 1024 + h * 64 + lq * 8;
    qf[0] = *(const s8v*)(Qb + base);
    qf[1] = *(const s8v*)(Qb + base + 32);
    sf[0] = *(const s8v*)(SPb + base);
    sf[1] = *(const s8v*)(SPb + base + 32);
  }
  const s8v ones = {0x3F80, 0x3F80, 0x3F80, 0x3F80, 0x3F80, 0x3F80, 0x3F80, 0x3F80};

  const f4v fz = {0.f, 0.f, 0.f, 0.f};
  f4v oacc[4], vs[4];
  float lacc[4];
#pragma unroll
  for (int i = 0; i < 4; ++i) { oacc[i] = fz; vs[i] = fz; lacc[i] = 0.f; }

  const int iqw = qt * 64 + w * 16;      // wave q-base
  const int srow = t >> 3;
  const int csw = ((t & 7) ^ (srow & 7)) * 8;  // staged global chunk (swizzle)
  const int rx = lr & 7;
  u16* pw = pbuf[w];

  for (int jc = jlo; jc <= jhi; ++jc) {
    const int j0 = jc * 64;
    __syncthreads();  // all waves done with previous chunk's LDS
    {
      const size_t kg = ((size_t)(b * 1024 + j0 + srow)) * 1024 + h * 64 + csw;
      gload16(Kb + kg, kbuf + t * 8);
      gload16(Kb + kg + 32 * 1024, kbuf + 2048 + t * 8);
      gload16(SPb + kg, skbuf + t * 8);
      gload16(SPb + kg + 32 * 1024, skbuf + 2048 + t * 8);
      const size_t vg = ((size_t)((b * 16 + h) * 64 + srow)) * 1024 + j0 + csw;
      gload16(Vt + vg, vbuf + t * 8);
      gload16(Vt + vg + 32 * 1024, vbuf + 2048 + t * 8);
    }
    __syncthreads();

    // ---- S^T: mfma(K-rows, Q-cols) -> C[j=ni*16+lq*4+r][i=lr] ------------
    f4v sa[4], ssa[4];
#pragma unroll
    for (int ni = 0; ni < 4; ++ni) { sa[ni] = fz; ssa[ni] = fz; }
#pragma unroll
    for (int ks = 0; ks < 2; ++ks) {
#pragma unroll
      for (int ni = 0; ni < 4; ++ni) {
        const int off = (ni * 16 + lr) * 64 + (((ks * 4 + lq) ^ rx) * 8);
        const s8v kf = *(const s8v*)(kbuf + off);
        sa[ni] = __builtin_amdgcn_mfma_f32_16x16x32_bf16(kf, qf[ks], sa[ni], 0, 0, 0);
        const s8v skf = *(const s8v*)(skbuf + off);
        ssa[ni] = __builtin_amdgcn_mfma_f32_16x16x32_bf16(skf, sf[ks], ssa[ni], 0, 0, 0);
      }
    }

    // ---- score modifiers + exp (no max subtraction) ----------------------
    const int D0 = iqw - j0;  // i - j = D0 + lr - j_loc
    float pv[4][4];
    if (jc < qt) {            // strictly below diagonal: i > j
      const float EA = K0 * fexp2(-c2 * (float)(D0 + lr));
#pragma unroll
      for (int ni = 0; ni < 4; ++ni)
#pragma unroll
        for (int r = 0; r < 4; ++r) {
          const float t1 = fmaf(ssa[ni][r], 0.125f, 1.0f);
          const float e = fexp2(sa[ni][r] * cN[ni] * cR[r] * EA * t1);
          pv[ni][r] = e;
          lacc[ni] += e;
        }
    } else if (jc > qt) {     // strictly above diagonal: i < j
      const float EAi = K0 * fexp2(c2 * (float)(D0 + lr));
#pragma unroll
      for (int ni = 0; ni < 4; ++ni)
#pragma unroll
        for (int r = 0; r < 4; ++r) {
          const float t1 = fmaf(ssa[ni][r], 0.125f, 1.0f);
          const float e = fexp2(sa[ni][r] * cNi[ni] * cRi[r] * EAi * t1);
          pv[ni][r] = e;
          lacc[ni] += e;
        }
    } else {                  // diagonal chunk: per-element side select
      const float EA  = K0 * fexp2(-c2 * (float)(D0 + lr));
      const float EAi = K0 * fexp2(c2 * (float)(D0 + lr));
#pragma unroll
      for (int ni = 0; ni < 4; ++ni)
#pragma unroll
        for (int r = 0; r < 4; ++r) {
          const int jloc = ni * 16 + lq * 4 + r;
          const float fb = cN[ni] * cR[r] * EA;
          const float fa = cNi[ni] * cRi[r] * EAi;
          const float f = (D0 + lr >= jloc) ? fb : fa;
          const float t1 = fmaf(ssa[ni][r], 0.125f, 1.0f);
          const float e = fexp2(sa[ni][r] * f * t1);
          pv[ni][r] = e;
          lacc[ni] += e;
        }
    }

    // ---- P[i][j] to LDS (b64 writes, XOR-swizzled chunks) ----------------
#pragma unroll
    for (int ni = 0; ni < 4; ++ni) {
      const int phys = (ni * 2 + (lq >> 1)) ^ rx;
      uint2 p2;
      p2.x = pk2(pv[ni][0], pv[ni][1]);
      p2.y = pk2(pv[ni][2], pv[ni][3]);
      *(uint2*)(pw + lr * 64 + phys * 8 + (lq & 1) * 4) = p2;
    }

    // ---- O^T += V^T @ P^T; vs += V^T @ ones (near-V column sums) ---------
#pragma unroll
    for (int ks = 0; ks < 2; ++ks) {
      const s8v pf = *(const s8v*)(pw + lr * 64 + (((ks * 4 + lq) ^ rx) * 8));
#pragma unroll
      for (int nd = 0; nd < 4; ++nd) {
        const int off = (nd * 16 + lr) * 64 + (((ks * 4 + lq) ^ rx) * 8);
        const s8v vf = *(const s8v*)(vbuf + off);
        oacc[nd] = __builtin_amdgcn_mfma_f32_16x16x32_bf16(vf, pf, oacc[nd], 0, 0, 0);
        vs[nd] = __builtin_amdgcn_mfma_f32_16x16x32_bf16(vf, ones, vs[nd], 0, 0, 0);
      }
    }
  }

  // ---- far field: oacc += Vtot - nearV; l += 64*farCnt; store ------------
  float ls = (lacc[0] + lacc[1]) + (lacc[2] + lacc[3]);
  ls += __shfl_xor(ls, 16);
  ls += __shfl_xor(ls, 32);
  ls += 64.0f * (float)farCnt;
  const float inv = 1.0f / ls;
  const float* vt0 = Vtot + (size_t)(b * 16 + h) * 64;
  const size_t orow = ((size_t)(b * 1024 + qt * 64 + w * 16 + lr)) * 1024 + h * 64;
#pragma unroll
  for (int nd = 0; nd < 4; ++nd) {
    const float4 vt4 = *(const float4*)(vt0 + nd * 16 + lq * 4);
    float o0 = (oacc[nd][0] + vt4.x - vs[nd][0]) * inv;
    float o1 = (oacc[nd][1] + vt4.y - vs[nd][1]) * inv;
    float o2 = (oacc[nd][2] + vt4.z - vs[nd][2]) * inv;
    float o3 = (oacc[nd][3] + vt4.w - vs[nd][3]) * inv;
    uint2 o;
    o.x = pk2r(o0, o1);
    o.y = pk2r(o2, o3);
    *(uint2*)(CTXb + orow + nd * 16 + lq * 4) = o;
  }
}

}  // namespace

extern "C" void kernel_launch(void* const* d_in, const int* in_sizes, int n_in,
                              void* d_out, int out_size, void* d_ws, size_t ws_size,
                              hipStream_t stream) {
  const float* x      = (const float*)d_in[0];
  const float* spikes = (const float*)d_in[1];
  const float* mem    = (const float*)d_in[2];
  const float* Wq     = (const float*)d_in[3];
  const float* bq     = (const float*)d_in[4];
  const float* Wk     = (const float*)d_in[5];
  const float* bk     = (const float*)d_in[6];
  const float* Wv     = (const float*)d_in[7];
  const float* bv     = (const float*)d_in[8];
  const float* Wo     = (const float*)d_in[9];
  const float* bo     = (const float*)d_in[10];
  const float* tau    = (const float*)d_in[11];
  const float* Wg     = (const float*)d_in[12];
  const float* bg     = (const float*)d_in[13];
  float* out = (float*)d_out;

  uint8_t* w8 = (uint8_t*)d_ws;
  u16* spb  = (u16*)(w8);                 // 8 MB
  u16* xb   = (u16*)(w8 + (8u << 20));    // 8 MB
  u16* Wqb  = (u16*)(w8 + (16u << 20));   // 2 MB
  u16* Wkb  = (u16*)(w8 + (18u << 20));   // 2 MB
  u16* Wvb  = (u16*)(w8 + (20u << 20));   // 2 MB
  u16* Wob  = (u16*)(w8 + (22u << 20));   // 2 MB
  u16* Wgb  = (u16*)(w8 + (24u << 20));   // 4 MB
  u16* Qb   = (u16*)(w8 + (28u << 20));   // 8 MB
  u16* Kb   = (u16*)(w8 + (36u << 20));   // 8 MB
  u16* Vt   = (u16*)(w8 + (44u << 20));   // 8 MB  [b,h,d,s]
  u16* CTXb = (u16*)(w8 + (52u << 20));   // 8 MB
  float* Vtot = (float*)(w8 + (60u << 20));  // 16 KB
  u16* memb = (u16*)d_out;  // 8 MB of the 16 MB fp32 out buffer; dead until
                            // the final out_gemm overwrites it
  u16* gctx = xb;           // x dead after QKV

  // 1) bf16 conversions (18 jobs) + Vtot zeroing (4 spare blocks)
  constexpr size_t QE = 262144 * 4;  // elements per job
  CvtArgs ca;
  for (int q = 0; q < 4; ++q) ca.j[q]     = {x + q * QE,      xb + q * QE};
  for (int q = 0; q < 4; ++q) ca.j[4 + q] = {spikes + q * QE, spb + q * QE};
  for (int q = 0; q < 4; ++q) ca.j[8 + q] = {mem + q * QE,    memb + q * QE};
  ca.j[12] = {Wq, Wqb};
  ca.j[13] = {Wk, Wkb};
  ca.j[14] = {Wv, Wvb};
  ca.j[15] = {Wo, Wob};
  ca.j[16] = {Wg, Wgb};
  ca.j[17] = {Wg + QE, Wgb + QE};
  ca.vz = Vtot;
  cvt_kernel<<<dim3(1024, 18), 256, 0, stream>>>(ca);

  // 2) QKV projection (direct-to-register, barrier-free; V gated+transposed,
  //    Vtot accumulated via atomics)
  qkv_gemm<<<dim3(24, 32), 256, 0, stream>>>(xb, Wqb, Wkb, Wvb, bq, bk, bv, mem,
                                             Qb, Kb, Vt, Vtot);
  // 3) flash attention (near chunks + far-field closed form, XCD swizzle)
  attn_mfma<<<dim3(1024), 256, 0, stream>>>(Qb, Kb, spb, Vt, tau, Vtot, CTXb);
  // 4) dendritic gate (K=2048 concat; mem-bf16 lives in d_out)
  gemm64<1, 32><<<dim3(8, 64), 256, 0, stream>>>(CTXb, memb, Wgb, bg, gctx, nullptr);
  // 5) output projection (fp32 out; overwrites memb region last)
  gemm64<0, 16><<<dim3(8, 64), 256, 0, stream>>>(gctx, nullptr, Wob, bo, nullptr, out);
}

// Round 12
// 259.505 us; speedup vs baseline: 1.5695x; 1.5695x over previous
//
#include <hip/hip_runtime.h>
#include <math.h>
#include <stdint.h>

namespace {

typedef __attribute__((ext_vector_type(8))) short s8v;   // 8 bf16 (MFMA A/B frag)
typedef __attribute__((ext_vector_type(4))) float f4v;   // MFMA C/D frag
typedef unsigned short u16;

__device__ __forceinline__ float fexp2(float x) {  // native v_exp_f32 (2^x)
  return __builtin_amdgcn_exp2f(x);
}

__device__ __forceinline__ u16 f2bf(float f) {  // RTNE
  union { float f; uint32_t u; } v; v.f = f;
  uint32_t r = v.u + 0x7fffu + ((v.u >> 16) & 1u);
  return (u16)(r >> 16);
}
__device__ __forceinline__ float bf2f(u16 h) {
  union { uint32_t u; float f; } v; v.u = ((uint32_t)h) << 16;
  return v.f;
}
__device__ __forceinline__ uint32_t pk2r(float a, float b) {  // RTNE pair pack
  return (uint32_t)f2bf(a) | ((uint32_t)f2bf(b) << 16);
}
__device__ __forceinline__ uint32_t pk2(float a, float b) {  // fast round-half-up
  union { float f; uint32_t u; } x, y; x.f = a; y.f = b;
  return ((x.u + 0x8000u) >> 16) | ((y.u + 0x8000u) & 0xffff0000u);
}
__device__ __forceinline__ float sigmoidf_(float x) { return 1.0f / (1.0f + __expf(-x)); }

__device__ __forceinline__ void gload16(const u16* g, u16* l) {
  __builtin_amdgcn_global_load_lds(
      (const __attribute__((address_space(1))) void*)g,
      (__attribute__((address_space(3))) void*)l, 16, 0, 0);
}

// ---------------------------------------------------------------------------
// fp32 -> bf16 conversion; equal jobs of 262144 float4-groups.
// Blocks (y==0, x<4) additionally zero Vtot (16 KB) for qkv's atomic sums.
// ---------------------------------------------------------------------------
struct CvtJob { const float* src; u16* dst; };
struct CvtArgs { CvtJob j[18]; float* vz; };

__global__ __launch_bounds__(256) void cvt_kernel(CvtArgs a) {
  if (blockIdx.y == 0 && blockIdx.x < 4) {
    float4 z; z.x = 0.f; z.y = 0.f; z.z = 0.f; z.w = 0.f;
    ((float4*)a.vz)[blockIdx.x * 256 + threadIdx.x] = z;
  }
  const CvtJob jb = a.j[blockIdx.y];
  const int i = blockIdx.x * 256 + threadIdx.x;
  const float4 v = ((const float4*)jb.src)[i];
  uint2 pk;
  pk.x = pk2r(v.x, v.y);
  pk.y = pk2r(v.z, v.w);
  ((uint2*)jb.dst)[i] = pk;
}

// ---------------------------------------------------------------------------
// Fused QKV projection, 128x128 tile, BK=64, swizzled 32 KB single-buffer
// LDS (3 blocks/CU, zero tail at 768 blocks), r6-style pipelined K-loop:
//   barrier -> ds_read frags -> barrier -> issue next chunk's loads -> MFMA.
// Q/K compute C^T via mfma(b,a) -> uint2 stores; V keeps mfma(a,b)
// (s-packed Vt[b][h][d][s] store) and atomically accumulates Vtot.
// ---------------------------------------------------------------------------
__global__ __launch_bounds__(256) void qkv_gemm(
    const u16* __restrict__ xb,
    const u16* __restrict__ Wqb, const u16* __restrict__ Wkb, const u16* __restrict__ Wvb,
    const float* __restrict__ bq, const float* __restrict__ bk, const float* __restrict__ bv,
    const float* __restrict__ mem,
    u16* __restrict__ Qb, u16* __restrict__ Kb, u16* __restrict__ Vt,
    float* __restrict__ Vtot) {
  __shared__ u16 as_[8192], bs_[8192];  // 128 rows x 64 k, swizzled
  const int t = threadIdx.x;
  const int nb = blockIdx.x, mb = blockIdx.y;
  const int sel = nb >> 3;
  const u16* W = sel == 0 ? Wqb : (sel == 1 ? Wkb : Wvb);
  const float* bias = sel == 0 ? bq : (sel == 1 ? bk : bv);
  const int m0 = mb * 128, n0 = (nb & 7) * 128;
  const f4v fz = {0.f, 0.f, 0.f, 0.f};
  f4v acc[4][4];
#pragma unroll
  for (int i = 0; i < 4; ++i)
#pragma unroll
    for (int j = 0; j < 4; ++j) acc[i][j] = fz;

  const int l = t & 63, w = t >> 6, wm = w >> 1, wn = w & 1;
  const int lr = l & 15, lq = l >> 4;
  const int rx = lr & 7;
  const int srow = t >> 3;                      // staging row 0..31 per round
  const int scol = ((t & 7) ^ (srow & 7)) * 8;  // swizzled 16B chunk (elems)

#define QKV_STAGE(k0)                                                          \
  {                                                                            \
    const int kk_ = (k0);                                                      \
    _Pragma("unroll") for (int u = 0; u < 4; ++u) {                            \
      gload16(xb + (size_t)(m0 + u * 32 + srow) * 1024 + kk_ + scol,           \
              as_ + u * 2048 + t * 8);                                         \
      gload16(W + (size_t)(n0 + u * 32 + srow) * 1024 + kk_ + scol,            \
              bs_ + u * 2048 + t * 8);                                         \
    }                                                                          \
  }

  QKV_STAGE(0);

  if (sel < 2) {  // ---- Q/K: swapped operands (C^T) ----
    for (int c = 0; c < 16; ++c) {
      __syncthreads();  // own vmcnt(0) + all waves: LDS(c) ready
      s8v af[2][4], bf[2][4];
#pragma unroll
      for (int ks = 0; ks < 2; ++ks) {
        const int co = ((ks * 4 + lq) ^ rx) * 8;
#pragma unroll
        for (int mi = 0; mi < 4; ++mi)
          af[ks][mi] = *(const s8v*)(as_ + (wm * 64 + mi * 16 + lr) * 64 + co);
#pragma unroll
        for (int ni = 0; ni < 4; ++ni)
          bf[ks][ni] = *(const s8v*)(bs_ + (wn * 64 + ni * 16 + lr) * 64 + co);
      }
      __syncthreads();  // all waves done reading LDS(c)
      if (c < 15) QKV_STAGE((c + 1) << 6);  // prefetch flies during MFMA
#pragma unroll
      for (int ks = 0; ks < 2; ++ks)
#pragma unroll
        for (int mi = 0; mi < 4; ++mi)
#pragma unroll
          for (int ni = 0; ni < 4; ++ni)
            acc[mi][ni] = __builtin_amdgcn_mfma_f32_16x16x32_bf16(
                bf[ks][ni], af[ks][mi], acc[mi][ni], 0, 0, 0);
    }
    u16* dst = (sel == 0) ? Qb : Kb;
#pragma unroll
    for (int mi = 0; mi < 4; ++mi)
#pragma unroll
      for (int ni = 0; ni < 4; ++ni) {
        const int m = m0 + wm * 64 + mi * 16 + lr;
        const int nb4 = n0 + wn * 64 + ni * 16 + lq * 4;
        const float4 b4 = *(const float4*)&bias[nb4];
        uint2 pk;
        pk.x = pk2r(acc[mi][ni][0] + b4.x, acc[mi][ni][1] + b4.y);
        pk.y = pk2r(acc[mi][ni][2] + b4.z, acc[mi][ni][3] + b4.w);
        *(uint2*)(dst + (size_t)m * 1024 + nb4) = pk;
      }
  } else {  // ---- V: normal operands (s-packed Vt store) + Vtot atomics ----
    for (int c = 0; c < 16; ++c) {
      __syncthreads();
      s8v af[2][4], bf[2][4];
#pragma unroll
      for (int ks = 0; ks < 2; ++ks) {
        const int co = ((ks * 4 + lq) ^ rx) * 8;
#pragma unroll
        for (int mi = 0; mi < 4; ++mi)
          af[ks][mi] = *(const s8v*)(as_ + (wm * 64 + mi * 16 + lr) * 64 + co);
#pragma unroll
        for (int ni = 0; ni < 4; ++ni)
          bf[ks][ni] = *(const s8v*)(bs_ + (wn * 64 + ni * 16 + lr) * 64 + co);
      }
      __syncthreads();
      if (c < 15) QKV_STAGE((c + 1) << 6);
#pragma unroll
      for (int ks = 0; ks < 2; ++ks)
#pragma unroll
        for (int mi = 0; mi < 4; ++mi)
#pragma unroll
          for (int ni = 0; ni < 4; ++ni)
            acc[mi][ni] = __builtin_amdgcn_mfma_f32_16x16x32_bf16(
                af[ks][mi], bf[ks][ni], acc[mi][ni], 0, 0, 0);
    }
    const int b = m0 >> 10;
    float vpart[4] = {0.f, 0.f, 0.f, 0.f};
#pragma unroll
    for (int mi = 0; mi < 4; ++mi)
#pragma unroll
      for (int ni = 0; ni < 4; ++ni) {
        const int mrow = m0 + wm * 64 + mi * 16 + lq * 4;
        const int ncol = n0 + wn * 64 + ni * 16 + lr;
        const int h = ncol >> 6, d = ncol & 63;
        const float bi = bias[ncol];
        float tv[4];
#pragma unroll
        for (int r = 0; r < 4; ++r)
          tv[r] = (acc[mi][ni][r] + bi) * sigmoidf_(mem[(size_t)(mrow + r) * 1024 + ncol]);
        vpart[ni] += (tv[0] + tv[1]) + (tv[2] + tv[3]);
        const int s = mrow & 1023;
        uint2 pk;
        pk.x = pk2r(tv[0], tv[1]);
        pk.y = pk2r(tv[2], tv[3]);
        *(uint2*)(Vt + ((size_t)((b * 16 + h) * 64 + d)) * 1024 + s) = pk;
      }
#pragma unroll
    for (int ni = 0; ni < 4; ++ni) {
      const int ncol = n0 + wn * 64 + ni * 16 + lr;
      atomicAdd(&Vtot[(size_t)(b * 16 + (ncol >> 6)) * 64 + (ncol & 63)], vpart[ni]);
    }
  }
#undef QKV_STAGE
}

// ---------------------------------------------------------------------------
// 64(M) x 128(N) GEMM, BK=64, swizzled LDS, dbuf K-loop, swapped operands.
// (round-10 version)
// MODE 0: out = A @ W^T + bias (fp32 out, float4 stores)
// MODE 1: gate: A = [Ab | A2b] (K=2048); out = Ab * sigmoid(A@Wg^T+bg) (bf16)
// ---------------------------------------------------------------------------
template <int MODE>
__global__ __launch_bounds__(256) void gemm64(
    const u16* __restrict__ Ab, const u16* __restrict__ A2b,
    const u16* __restrict__ W, const float* __restrict__ bias,
    u16* __restrict__ outb, float* __restrict__ outf, int K) {
  __shared__ u16 as_[8192], bs_[16384];  // 2 x (64x64 / 128x64), swizzled
  const int t = threadIdx.x, l = t & 63, w = t >> 6;
  const int wm = w >> 1, wn = w & 1, lr = l & 15, lq = l >> 4;
  const int m0 = blockIdx.y * 64, n0 = blockIdx.x * 128;
  const f4v fz = {0.f, 0.f, 0.f, 0.f};
  f4v acc[2][4];
#pragma unroll
  for (int i = 0; i < 2; ++i)
#pragma unroll
    for (int j = 0; j < 4; ++j) acc[i][j] = fz;
  const int rx = lr & 7;
  const int srow = t >> 3;
  const int scol = ((t & 7) ^ (srow & 7)) * 8;
  const int nc = K >> 6;

#define G64_STAGE(k0, bsel)                                                    \
  {                                                                            \
    const int kk_ = (k0);                                                      \
    const u16* Ae_ = Ab;                                                       \
    int ka_ = kk_;                                                             \
    if (MODE == 1 && kk_ >= 1024) { Ae_ = A2b; ka_ = kk_ - 1024; }             \
    _Pragma("unroll") for (int u = 0; u < 2; ++u)                              \
        gload16(Ae_ + (size_t)(m0 + u * 32 + srow) * 1024 + ka_ + scol,        \
                as_ + (bsel) * 4096 + u * 2048 + t * 8);                       \
    _Pragma("unroll") for (int u = 0; u < 4; ++u)                              \
        gload16(W + (size_t)(n0 + u * 32 + srow) * K + kk_ + scol,             \
                bs_ + (bsel) * 8192 + u * 2048 + t * 8);                       \
  }

  G64_STAGE(0, 0);
  int pp = 0;
  for (int c = 0; c < nc; ++c) {
    __syncthreads();  // drains chunk-c loads; all waves done with buf pp^1
    if (c + 1 < nc) G64_STAGE((c + 1) << 6, pp ^ 1);  // flies behind compute
    const int loA = pp * 4096, loB = pp * 8192;
#pragma unroll
    for (int ks = 0; ks < 2; ++ks) {
      const int co = ((ks * 4 + lq) ^ rx) * 8;
      s8v af[2], bf[4];
#pragma unroll
      for (int mi = 0; mi < 2; ++mi)
        af[mi] = *(const s8v*)(as_ + loA + (wm * 32 + mi * 16 + lr) * 64 + co);
#pragma unroll
      for (int ni = 0; ni < 4; ++ni)
        bf[ni] = *(const s8v*)(bs_ + loB + (wn * 64 + ni * 16 + lr) * 64 + co);
#pragma unroll
      for (int mi = 0; mi < 2; ++mi)
#pragma unroll
        for (int ni = 0; ni < 4; ++ni)
          acc[mi][ni] = __builtin_amdgcn_mfma_f32_16x16x32_bf16(
              bf[ni], af[mi], acc[mi][ni], 0, 0, 0);
    }
    pp ^= 1;
  }
#undef G64_STAGE

#pragma unroll
  for (int mi = 0; mi < 2; ++mi)
#pragma unroll
    for (int ni = 0; ni < 4; ++ni) {
      const int m = m0 + wm * 32 + mi * 16 + lr;
      const int nb4 = n0 + wn * 64 + ni * 16 + lq * 4;
      const float4 b4 = *(const float4*)&bias[nb4];
      if (MODE == 0) {
        float4 o;
        o.x = acc[mi][ni][0] + b4.x; o.y = acc[mi][ni][1] + b4.y;
        o.z = acc[mi][ni][2] + b4.z; o.w = acc[mi][ni][3] + b4.w;
        *(float4*)(outf + (size_t)m * 1024 + nb4) = o;
      } else {
        const uint2 a2 = *(const uint2*)(Ab + (size_t)m * 1024 + nb4);
        float cx[4] = {bf2f((u16)(a2.x & 0xffff)), bf2f((u16)(a2.x >> 16)),
                       bf2f((u16)(a2.y & 0xffff)), bf2f((u16)(a2.y >> 16))};
        float g[4];
        g[0] = cx[0] * sigmoidf_(acc[mi][ni][0] + b4.x);
        g[1] = cx[1] * sigmoidf_(acc[mi][ni][1] + b4.y);
        g[2] = cx[2] * sigmoidf_(acc[mi][ni][2] + b4.z);
        g[3] = cx[3] * sigmoidf_(acc[mi][ni][3] + b4.w);
        uint2 pk;
        pk.x = pk2r(g[0], g[1]);
        pk.y = pk2r(g[2], g[3]);
        *(uint2*)(outb + (size_t)m * 1024 + nb4) = pk;
      }
    }
}

// ---------------------------------------------------------------------------
// MFMA flash attention with far-field truncation (round-10 structure).
// ---------------------------------------------------------------------------
__global__ __launch_bounds__(256) void attn_mfma(
    const u16* __restrict__ Qb, const u16* __restrict__ Kb,
    const u16* __restrict__ SPb, const u16* __restrict__ Vt,
    const float* __restrict__ tau, const float* __restrict__ Vtot,
    u16* __restrict__ CTXb) {
  __shared__ u16 kbuf[4096], skbuf[4096], vbuf[4096];
  __shared__ u16 pbuf[4][16 * 64];  // per-wave P[i][j], XOR-swizzled 16B chunks
  const int t = threadIdx.x, l = t & 63, w = t >> 6;
  const int lr = l & 15, lq = l >> 4;
  const int p = blockIdx.x;
  const int g = (p & 7) + 8 * (p >> 7);   // bh-group 0..63
  const int qt = (p >> 3) & 15;
  const int h = g & 15, b = g >> 4;

  const float tv_ = tau[h];
  const float c2 = 1.44269504088896f / tv_;     // log2e / tau
  const float K0 = 0.125f * 1.44269504088896f;  // scale * log2e
  int rad = (int)ceilf(tv_ * 0.171875f);  // 11/64: far scores <6e-5 -> P==1
  if (rad > 15) rad = 15;
  const int jlo = (qt - rad < 0) ? 0 : qt - rad;
  const int jhi = (qt + rad > 15) ? 15 : qt + rad;
  const int farCnt = 16 - (jhi - jlo + 1);

  float cN[4], cNi[4], cR[4], cRi[4];
#pragma unroll
  for (int i = 0; i < 4; ++i) {
    cN[i]  = fexp2(c2 * (float)(i * 16));
    cNi[i] = fexp2(-c2 * (float)(i * 16));
    cR[i]  = fexp2(c2 * (float)(lq * 4 + i));
    cRi[i] = fexp2(-c2 * (float)(lq * 4 + i));
  }

  s8v qf[2], sf[2];
  {
    const size_t base = ((size_t)(b * 1024 + qt * 64 + w * 16 + lr)) * 1024 + h * 64 + lq * 8;
    qf[0] = *(const s8v*)(Qb + base);
    qf[1] = *(const s8v*)(Qb + base + 32);
    sf[0] = *(const s8v*)(SPb + base);
    sf[1] = *(const s8v*)(SPb + base + 32);
  }
  const s8v ones = {0x3F80, 0x3F80, 0x3F80, 0x3F80, 0x3F80, 0x3F80, 0x3F80, 0x3F80};

  const f4v fz = {0.f, 0.f, 0.f, 0.f};
  f4v oacc[4], vs[4];
  float lacc[4];
#pragma unroll
  for (int i = 0; i < 4; ++i) { oacc[i] = fz; vs[i] = fz; lacc[i] = 0.f; }

  const int iqw = qt * 64 + w * 16;      // wave q-base
  const int srow = t >> 3;
  const int csw = ((t & 7) ^ (srow & 7)) * 8;  // staged global chunk (swizzle)
  const int rx = lr & 7;
  u16* pw = pbuf[w];

  for (int jc = jlo; jc <= jhi; ++jc) {
    const int j0 = jc * 64;
    __syncthreads();  // all waves done with previous chunk's LDS
    {
      const size_t kg = ((size_t)(b * 1024 + j0 + srow)) * 1024 + h * 64 + csw;
      gload16(Kb + kg, kbuf + t * 8);
      gload16(Kb + kg + 32 * 1024, kbuf + 2048 + t * 8);
      gload16(SPb + kg, skbuf + t * 8);
      gload16(SPb + kg + 32 * 1024, skbuf + 2048 + t * 8);
      const size_t vg = ((size_t)((b * 16 + h) * 64 + srow)) * 1024 + j0 + csw;
      gload16(Vt + vg, vbuf + t * 8);
      gload16(Vt + vg + 32 * 1024, vbuf + 2048 + t * 8);
    }
    __syncthreads();

    // ---- S^T: mfma(K-rows, Q-cols) -> C[j=ni*16+lq*4+r][i=lr] ------------
    f4v sa[4], ssa[4];
#pragma unroll
    for (int ni = 0; ni < 4; ++ni) { sa[ni] = fz; ssa[ni] = fz; }
#pragma unroll
    for (int ks = 0; ks < 2; ++ks) {
#pragma unroll
      for (int ni = 0; ni < 4; ++ni) {
        const int off = (ni * 16 + lr) * 64 + (((ks * 4 + lq) ^ rx) * 8);
        const s8v kf = *(const s8v*)(kbuf + off);
        sa[ni] = __builtin_amdgcn_mfma_f32_16x16x32_bf16(kf, qf[ks], sa[ni], 0, 0, 0);
        const s8v skf = *(const s8v*)(skbuf + off);
        ssa[ni] = __builtin_amdgcn_mfma_f32_16x16x32_bf16(skf, sf[ks], ssa[ni], 0, 0, 0);
      }
    }

    // ---- score modifiers + exp (no max subtraction) ----------------------
    const int D0 = iqw - j0;  // i - j = D0 + lr - j_loc
    float pv[4][4];
    if (jc < qt) {            // strictly below diagonal: i > j
      const float EA = K0 * fexp2(-c2 * (float)(D0 + lr));
#pragma unroll
      for (int ni = 0; ni < 4; ++ni)
#pragma unroll
        for (int r = 0; r < 4; ++r) {
          const float t1 = fmaf(ssa[ni][r], 0.125f, 1.0f);
          const float e = fexp2(sa[ni][r] * cN[ni] * cR[r] * EA * t1);
          pv[ni][r] = e;
          lacc[ni] += e;
        }
    } else if (jc > qt) {     // strictly above diagonal: i < j
      const float EAi = K0 * fexp2(c2 * (float)(D0 + lr));
#pragma unroll
      for (int ni = 0; ni < 4; ++ni)
#pragma unroll
        for (int r = 0; r < 4; ++r) {
          const float t1 = fmaf(ssa[ni][r], 0.125f, 1.0f);
          const float e = fexp2(sa[ni][r] * cNi[ni] * cRi[r] * EAi * t1);
          pv[ni][r] = e;
          lacc[ni] += e;
        }
    } else {                  // diagonal chunk: per-element side select
      const float EA  = K0 * fexp2(-c2 * (float)(D0 + lr));
      const float EAi = K0 * fexp2(c2 * (float)(D0 + lr));
#pragma unroll
      for (int ni = 0; ni < 4; ++ni)
#pragma unroll
        for (int r = 0; r < 4; ++r) {
          const int jloc = ni * 16 + lq * 4 + r;
          const float fb = cN[ni] * cR[r] * EA;
          const float fa = cNi[ni] * cRi[r] * EAi;
          const float f = (D0 + lr >= jloc) ? fb : fa;
          const float t1 = fmaf(ssa[ni][r], 0.125f, 1.0f);
          const float e = fexp2(sa[ni][r] * f * t1);
          pv[ni][r] = e;
          lacc[ni] += e;
        }
    }

    // ---- P[i][j] to LDS (b64 writes, XOR-swizzled chunks) ----------------
#pragma unroll
    for (int ni = 0; ni < 4; ++ni) {
      const int phys = (ni * 2 + (lq >> 1)) ^ rx;
      uint2 p2;
      p2.x = pk2(pv[ni][0], pv[ni][1]);
      p2.y = pk2(pv[ni][2], pv[ni][3]);
      *(uint2*)(pw + lr * 64 + phys * 8 + (lq & 1) * 4) = p2;
    }

    // ---- O^T += V^T @ P^T; vs += V^T @ ones (near-V column sums) ---------
#pragma unroll
    for (int ks = 0; ks < 2; ++ks) {
      const s8v pf = *(const s8v*)(pw + lr * 64 + (((ks * 4 + lq) ^ rx) * 8));
#pragma unroll
      for (int nd = 0; nd < 4; ++nd) {
        const int off = (nd * 16 + lr) * 64 + (((ks * 4 + lq) ^ rx) * 8);
        const s8v vf = *(const s8v*)(vbuf + off);
        oacc[nd] = __builtin_amdgcn_mfma_f32_16x16x32_bf16(vf, pf, oacc[nd], 0, 0, 0);
        vs[nd] = __builtin_amdgcn_mfma_f32_16x16x32_bf16(vf, ones, vs[nd], 0, 0, 0);
      }
    }
  }

  // ---- far field: oacc += Vtot - nearV; l += 64*farCnt; store ------------
  float ls = (lacc[0] + lacc[1]) + (lacc[2] + lacc[3]);
  ls += __shfl_xor(ls, 16);
  ls += __shfl_xor(ls, 32);
  ls += 64.0f * (float)farCnt;
  const float inv = 1.0f / ls;
  const float* vt0 = Vtot + (size_t)(b * 16 + h) * 64;
  const size_t orow = ((size_t)(b * 1024 + qt * 64 + w * 16 + lr)) * 1024 + h * 64;
#pragma unroll
  for (int nd = 0; nd < 4; ++nd) {
    const float4 vt4 = *(const float4*)(vt0 + nd * 16 + lq * 4);
    float o0 = (oacc[nd][0] + vt4.x - vs[nd][0]) * inv;
    float o1 = (oacc[nd][1] + vt4.y - vs[nd][1]) * inv;
    float o2 = (oacc[nd][2] + vt4.z - vs[nd][2]) * inv;
    float o3 = (oacc[nd][3] + vt4.w - vs[nd][3]) * inv;
    uint2 o;
    o.x = pk2r(o0, o1);
    o.y = pk2r(o2, o3);
    *(uint2*)(CTXb + orow + nd * 16 + lq * 4) = o;
  }
}

}  // namespace

extern "C" void kernel_launch(void* const* d_in, const int* in_sizes, int n_in,
                              void* d_out, int out_size, void* d_ws, size_t ws_size,
                              hipStream_t stream) {
  const float* x      = (const float*)d_in[0];
  const float* spikes = (const float*)d_in[1];
  const float* mem    = (const float*)d_in[2];
  const float* Wq     = (const float*)d_in[3];
  const float* bq     = (const float*)d_in[4];
  const float* Wk     = (const float*)d_in[5];
  const float* bk     = (const float*)d_in[6];
  const float* Wv     = (const float*)d_in[7];
  const float* bv     = (const float*)d_in[8];
  const float* Wo     = (const float*)d_in[9];
  const float* bo     = (const float*)d_in[10];
  const float* tau    = (const float*)d_in[11];
  const float* Wg     = (const float*)d_in[12];
  const float* bg     = (const float*)d_in[13];
  float* out = (float*)d_out;

  uint8_t* w8 = (uint8_t*)d_ws;
  u16* spb  = (u16*)(w8);                 // 8 MB
  u16* xb   = (u16*)(w8 + (8u << 20));    // 8 MB
  u16* Wqb  = (u16*)(w8 + (16u << 20));   // 2 MB
  u16* Wkb  = (u16*)(w8 + (18u << 20));   // 2 MB
  u16* Wvb  = (u16*)(w8 + (20u << 20));   // 2 MB
  u16* Wob  = (u16*)(w8 + (22u << 20));   // 2 MB
  u16* Wgb  = (u16*)(w8 + (24u << 20));   // 4 MB
  u16* Qb   = (u16*)(w8 + (28u << 20));   // 8 MB
  u16* Kb   = (u16*)(w8 + (36u << 20));   // 8 MB
  u16* Vt   = (u16*)(w8 + (44u << 20));   // 8 MB  [b,h,d,s]
  u16* CTXb = (u16*)(w8 + (52u << 20));   // 8 MB
  float* Vtot = (float*)(w8 + (60u << 20));  // 16 KB
  u16* memb = (u16*)d_out;  // 8 MB of the 16 MB fp32 out buffer; dead until
                            // the final out_gemm overwrites it
  u16* gctx = xb;           // x dead after QKV

  // 1) bf16 conversions (18 jobs) + Vtot zeroing (4 spare blocks)
  constexpr size_t QE = 262144 * 4;  // elements per job
  CvtArgs ca;
  for (int q = 0; q < 4; ++q) ca.j[q]     = {x + q * QE,      xb + q * QE};
  for (int q = 0; q < 4; ++q) ca.j[4 + q] = {spikes + q * QE, spb + q * QE};
  for (int q = 0; q < 4; ++q) ca.j[8 + q] = {mem + q * QE,    memb + q * QE};
  ca.j[12] = {Wq, Wqb};
  ca.j[13] = {Wk, Wkb};
  ca.j[14] = {Wv, Wvb};
  ca.j[15] = {Wo, Wob};
  ca.j[16] = {Wg, Wgb};
  ca.j[17] = {Wg + QE, Wgb + QE};
  ca.vz = Vtot;
  cvt_kernel<<<dim3(1024, 18), 256, 0, stream>>>(ca);

  // 2) QKV projection (32 KB LDS, 3 blocks/CU; V gated + transposed; Vtot
  //    accumulated via atomics -- no separate vsum launch)
  qkv_gemm<<<dim3(24, 32), 256, 0, stream>>>(xb, Wqb, Wkb, Wvb, bq, bk, bv, mem,
                                             Qb, Kb, Vt, Vtot);
  // 3) flash attention (near chunks + far-field closed form, XCD swizzle)
  attn_mfma<<<dim3(1024), 256, 0, stream>>>(Qb, Kb, spb, Vt, tau, Vtot, CTXb);
  // 4) dendritic gate (K=2048 concat; mem-bf16 lives in d_out)
  gemm64<1><<<dim3(8, 64), 256, 0, stream>>>(CTXb, memb, Wgb, bg, gctx, nullptr, 2048);
  // 5) output projection (fp32 out; overwrites memb region last)
  gemm64<0><<<dim3(8, 64), 256, 0, stream>>>(gctx, nullptr, Wob, bo, nullptr, out, 1024);
}